// Round 3
// baseline (85.174 us; speedup 1.0000x reference)
//
#include <hip/hip_runtime.h>
#include <hip/hip_bf16.h>

// ---------------------------------------------------------------------------
// Single fused kernel. One block per image (2048 blocks x 256 threads).
//
// Per block:
//  - threads 240..255: evolve the 16 basis states through the L-layer circuit
//    (RY,RZ per qubit + CNOT(0,1), CNOT(2,3)) -> U columns -> LDS (validated
//    math from rounds 1-2, absmax 0.0).
//  - threads 0..195 (concurrent, different waves): psi0[16] per 2x2 patch
//    from 4 sincos -> LDS.
//  - sync; each lane a=tid&15 pulls U row a into 32 VGPRs.
//  - main loop: 16 groups x 13 iters cover 196 patches; per patch 4x
//    ds_read_b128 (psi broadcast), 32 FMA complex matvec, |A|^2, 4-stage
//    signed WHT butterfly via shfl_xor -> z_q at lane 8>>q -> qf LDS.
//  - Phase B: GEMV 784->10 vs Wc (L2-resident) + log_softmax (validated).
// ---------------------------------------------------------------------------
#define NP 196      // patches per image
#define PSTRIDE 20  // psi row stride in floats (80 B: 16B-aligned, bank-spread)

__global__ __launch_bounds__(256) void quanv_fused_kernel(
    const float* __restrict__ x, const float* __restrict__ Wc,
    const float* __restrict__ bc, const float* __restrict__ w,
    const int L, float* __restrict__ out)
{
    const int b   = blockIdx.x;
    const int tid = threadIdx.x;
    const int a   = tid & 15;   // amplitude row
    const int g   = tid >> 4;   // group (patch slot)

    __shared__ __align__(16) float Urs[16][16];   // U real, [row][col]
    __shared__ __align__(16) float Uis[16][16];   // U imag
    __shared__ __align__(16) float psi_s[NP][PSTRIDE];
    __shared__ float qf[784];
    __shared__ float red[40];
    __shared__ float logits_s[10];

    // ---- In-block U construction (threads 240..255 = wave 3 lanes 48..63)
    if (tid >= 240) {
        const int j = tid - 240;   // basis state / U column
        float ar[16], ai[16];
#pragma unroll
        for (int k = 0; k < 16; ++k) { ar[k] = (k == j) ? 1.f : 0.f; ai[k] = 0.f; }

        for (int l = 0; l < L; ++l) {
#pragma unroll
            for (int q = 0; q < 4; ++q) {
                const float thy = w[l * 8 + q * 2 + 0];
                const float thz = w[l * 8 + q * 2 + 1];
                float cy, sy, cz, sz;
                __sincosf(0.5f * thy, &sy, &cy);
                __sincosf(0.5f * thz, &sz, &cz);
                const int st = 8 >> q;
                // RY on wire q
#pragma unroll
                for (int idx = 0; idx < 16; ++idx) {
                    if ((idx & st) == 0) {
                        const int i1 = idx + st;
                        const float a0r = ar[idx], a1r = ar[i1];
                        const float a0i = ai[idx], a1i = ai[i1];
                        ar[idx] = cy * a0r - sy * a1r;  ar[i1] = sy * a0r + cy * a1r;
                        ai[idx] = cy * a0i - sy * a1i;  ai[i1] = sy * a0i + cy * a1i;
                    }
                }
                // RZ on wire q
#pragma unroll
                for (int idx = 0; idx < 16; ++idx) {
                    const float r = ar[idx], im = ai[idx];
                    if ((idx & st) == 0) {
                        ar[idx] = r * cz + im * sz;
                        ai[idx] = im * cz - r * sz;
                    } else {
                        ar[idx] = r * cz - im * sz;
                        ai[idx] = im * cz + r * sz;
                    }
                }
            }
            // CNOT(0,1): control mask 8, target mask 4
#pragma unroll
            for (int idx = 0; idx < 16; ++idx) {
                if ((idx & 8) && !(idx & 4)) {
                    const int i2 = idx | 4;
                    float tr = ar[idx], ti = ai[idx];
                    ar[idx] = ar[i2]; ai[idx] = ai[i2];
                    ar[i2] = tr;      ai[i2] = ti;
                }
            }
            // CNOT(2,3): control mask 2, target mask 1
#pragma unroll
            for (int idx = 0; idx < 16; ++idx) {
                if ((idx & 2) && !(idx & 1)) {
                    const int i2 = idx | 1;
                    float tr = ar[idx], ti = ai[idx];
                    ar[idx] = ar[i2]; ai[idx] = ai[i2];
                    ar[i2] = tr;      ai[i2] = ti;
                }
            }
        }
#pragma unroll
        for (int aa = 0; aa < 16; ++aa) {
            Urs[aa][j] = ar[aa];
            Uis[aa][j] = ai[aa];
        }
    }

    // ---- psi pre-pass (threads 0..195, concurrent with U construction)
    if (tid < NP) {
        const int pi = tid / 14, pj = tid % 14;
        const float* xb = x + b * 784 + pi * 56 + pj * 2;
        const float d0 = xb[0], d1 = xb[1], d2 = xb[28], d3 = xb[29];

        float c0, s0, c1, s1, c2, s2, c3, s3;
        __sincosf(0.5f * d0, &s0, &c0);
        __sincosf(0.5f * d1, &s1, &c1);
        __sincosf(0.5f * d2, &s2, &c2);
        __sincosf(0.5f * d3, &s3, &c3);

        const float w0[2] = {c0, s0}, w1[2] = {c1, s1};
        const float w2[2] = {c2, s2}, w3[2] = {c3, s3};
#pragma unroll
        for (int i0 = 0; i0 < 2; ++i0)
#pragma unroll
            for (int i1 = 0; i1 < 2; ++i1) {
                const float ab = w0[i0] * w1[i1];
#pragma unroll
                for (int i2 = 0; i2 < 2; ++i2) {
                    const float abc = ab * w2[i2];
                    psi_s[tid][i0 * 8 + i1 * 4 + i2 * 2 + 0] = abc * w3[0];
                    psi_s[tid][i0 * 8 + i1 * 4 + i2 * 2 + 1] = abc * w3[1];
                }
            }
    }

    // WHT sign factors: sgn[s] = (a & (1<<s)) ? -1 : +1
    float sgn[4];
#pragma unroll
    for (int s = 0; s < 4; ++s) sgn[s] = (tid & (1 << s)) ? -1.f : 1.f;

    __syncthreads();

    // ---- U row a -> registers (8x ds_read_b128, once)
    float Ur[16], Ui[16];
    {
        const float4* r4 = (const float4*)&Urs[a][0];
        const float4* i4 = (const float4*)&Uis[a][0];
#pragma unroll
        for (int jj = 0; jj < 4; ++jj) {
            const float4 r  = r4[jj];
            const float4 im = i4[jj];
            Ur[4 * jj + 0] = r.x;  Ur[4 * jj + 1] = r.y;
            Ur[4 * jj + 2] = r.z;  Ur[4 * jj + 3] = r.w;
            Ui[4 * jj + 0] = im.x; Ui[4 * jj + 1] = im.y;
            Ui[4 * jj + 2] = im.z; Ui[4 * jj + 3] = im.w;
        }
    }

    // ---- Main loop: 13 iterations x 16 groups = 208 slots (>=196 clamped)
#pragma unroll 1
    for (int it = 0; it < 13; ++it) {
        const int p  = it * 16 + g;
        const int pc = (p < NP) ? p : (NP - 1);

        float psi[16];
        {
            const float4* prow = (const float4*)&psi_s[pc][0];
#pragma unroll
            for (int jj = 0; jj < 4; ++jj) {
                const float4 v = prow[jj];
                psi[4 * jj + 0] = v.x; psi[4 * jj + 1] = v.y;
                psi[4 * jj + 2] = v.z; psi[4 * jj + 3] = v.w;
            }
        }

        float Ar = 0.f, Ai = 0.f;
#pragma unroll
        for (int k = 0; k < 16; ++k) {
            Ar = fmaf(Ur[k], psi[k], Ar);
            Ai = fmaf(Ui[k], psi[k], Ai);
        }
        float v = Ar * Ar + Ai * Ai;

        // signed WHT butterfly over the 16-lane group -> z_q at lane 8>>q
#pragma unroll
        for (int s = 0; s < 4; ++s) {
            const float t = __shfl_xor(v, 1 << s, 64);
            v = fmaf(sgn[s], v, t);
        }
        if (p < NP) {
            if (a == 8)      qf[p * 4 + 0] = v;
            else if (a == 4) qf[p * 4 + 1] = v;
            else if (a == 2) qf[p * 4 + 2] = v;
            else if (a == 1) qf[p * 4 + 3] = v;
        }
    }
    __syncthreads();

    // ---- Phase B: GEMV (784 -> 10) + log_softmax
    float acc[10];
#pragma unroll
    for (int k = 0; k < 10; ++k) acc[k] = 0.f;

    for (int f = tid; f < 784; f += 256) {
        const float v = qf[f];
#pragma unroll
        for (int k = 0; k < 10; ++k)
            acc[k] = fmaf(v, Wc[k * 784 + f], acc[k]);
    }

#pragma unroll
    for (int k = 0; k < 10; ++k) {
#pragma unroll
        for (int off = 32; off > 0; off >>= 1)
            acc[k] += __shfl_down(acc[k], off, 64);
    }
    const int wave = tid >> 6;
    const int lane = tid & 63;
    if (lane == 0) {
#pragma unroll
        for (int k = 0; k < 10; ++k) red[wave * 10 + k] = acc[k];
    }
    __syncthreads();

    if (tid < 10)
        logits_s[tid] = bc[tid] + red[tid] + red[10 + tid] + red[20 + tid] + red[30 + tid];
    __syncthreads();

    if (tid < 10) {
        float m = logits_s[0];
#pragma unroll
        for (int jj = 1; jj < 10; ++jj) m = fmaxf(m, logits_s[jj]);
        float se = 0.f;
#pragma unroll
        for (int jj = 0; jj < 10; ++jj) se += __expf(logits_s[jj] - m);
        out[b * 10 + tid] = logits_s[tid] - m - __logf(se);
    }
}

// ---------------------------------------------------------------------------
extern "C" void kernel_launch(void* const* d_in, const int* in_sizes, int n_in,
                              void* d_out, int out_size, void* d_ws, size_t ws_size,
                              hipStream_t stream)
{
    const float* x  = (const float*)d_in[0];   // (B,1,28,28)
    const float* w  = (const float*)d_in[1];   // (L,4,2)
    const float* Wc = (const float*)d_in[2];   // (10,784)
    const float* bc = (const float*)d_in[3];   // (10,)
    float* out = (float*)d_out;                // (B,10)

    const int L = in_sizes[1] / 8;
    const int B = in_sizes[0] / 784;

    quanv_fused_kernel<<<B, 256, 0, stream>>>(x, Wc, bc, w, L, out);
}